// Round 7
// baseline (2416.047 us; speedup 1.0000x reference)
//
#include <hip/hip_runtime.h>
#include <stdint.h>

#define HW 16384
#define CDIM 768
#define EPSF 1e-8f

typedef float f32x4 __attribute__((ext_vector_type(4)));
typedef int   i32x8 __attribute__((ext_vector_type(8)));
typedef uint32_t u32x4 __attribute__((ext_vector_type(4)));

__device__ inline void async16(const void* g, void* l) {
    __builtin_amdgcn_global_load_lds(
        (const __attribute__((address_space(1))) uint32_t*)g,
        (__attribute__((address_space(3))) uint32_t*)l, 16, 0, 0);
}

__device__ inline uint32_t pk4_fp8(float v0, float v1, float v2, float v3) {
    uint32_t r = __builtin_amdgcn_cvt_pk_fp8_f32(v0, v1, 0, false);
    r = __builtin_amdgcn_cvt_pk_fp8_f32(v2, v3, r, true);
    return r;   // bytes [v0,v1,v2,v3] little-endian
}

// ---- Kernel 1: fused transpose [C][HW] fp32 -> [HW][C] fp8 + column sum-sq ----
// z=0: a (scale x16), z=1: b (scale x8, RAW; normalization in GEMM epilogue).
// Plain row-major fp8 output (u32 packed stores); sum-sq via one atomicAdd
// per (column, c-tile).
__global__ void __launch_bounds__(256)
transpose_fp8_norm(const float* __restrict__ a, const float* __restrict__ b,
                   uint8_t* __restrict__ at8, uint8_t* __restrict__ bn8,
                   float* __restrict__ sumsq_a, float* __restrict__ sumsq_b) {
    const int z = blockIdx.z;
    const float* src = z ? b : a;
    uint8_t* dst = z ? bn8 : at8;
    float* sums = z ? sumsq_b : sumsq_a;
    const float mult = z ? 8.0f : 16.0f;

    __shared__ float tile[64][65];   // [channel][spatial], +1 pad
    const int s0 = blockIdx.x * 64, c0 = blockIdx.y * 64;
    const int tx = threadIdx.x & 63, ty = threadIdx.x >> 6;
#pragma unroll
    for (int p = 0; p < 16; ++p) {
        int cl = p * 4 + ty;
        tile[cl][tx] = src[(size_t)(c0 + cl) * HW + s0 + tx];
    }
    __syncthreads();

    const int chgrp = tx & 15, rowsub = tx >> 4;
    uint32_t* dst32 = (uint32_t*)dst;
#pragma unroll
    for (int p = 0; p < 4; ++p) {
        int sl = p * 16 + ty * 4 + rowsub;
        float v0 = tile[chgrp * 4 + 0][sl];
        float v1 = tile[chgrp * 4 + 1][sl];
        float v2 = tile[chgrp * 4 + 2][sl];
        float v3 = tile[chgrp * 4 + 3][sl];
        float part = v0 * v0 + v1 * v1 + v2 * v2 + v3 * v3;  // raw sum-sq
        dst32[(size_t)(s0 + sl) * (CDIM / 4) + (c0 >> 2) + chgrp] =
            pk4_fp8(v0 * mult, v1 * mult, v2 * mult, v3 * mult);
#pragma unroll
        for (int m = 1; m < 16; m <<= 1) part += __shfl_xor(part, m, 64);
        if (chgrp == 0) atomicAdd(&sums[s0 + sl], part);
    }
}

// ---- Kernel 2: MX-scaled fp8 GEMM (K=128) + normalize + argmax epilogue ----
// Round-5 2-barrier structure (the proven plateau), upgraded per the m148
// ladder step: BK=128, mfma_scale_f32_16x16x128_f8f6f4 with E8M0 scale=127
// (x1.0 -> numerics identical to plain fp8). Halves barrier drains (12->6)
// and quarters MFMA instruction count. LDS 2x16 KB panels, row stride 128 B.
// Chunk-XOR swizzle: staging lane l loads global 16B-chunk (l&7)^(l>>3) of
// row l>>3 (per 8-row issue), so logical chunk c of row r sits at physical
// chunk c^(r&7) -> every b128 frag read is 2-way (free). 4 blocks/CU.
__global__ void __launch_bounds__(256, 4)
gemm_argmax(const uint8_t* __restrict__ at8, const uint8_t* __restrict__ bn8,
            const float* __restrict__ sumsq_b,
            unsigned long long* __restrict__ best) {
    __shared__ uint8_t Al[128 * 128];
    __shared__ uint8_t Bl[128 * 128];

    const int g = blockIdx.x;          // 0..16383
    const int xcd    = g & 7;
    const int s      = g >> 3;
    const int super  = s >> 5;         // 32 blocks / supertile
    const int within = s & 31;
    const int si = super >> 4;         // 4 i-tiles per supertile row
    const int sj = super & 15;         // 8 j-tiles per supertile col
    const int it = xcd * 16 + si * 4 + (within & 3);
    const int jt = sj * 8 + (within >> 2);

    const int i0 = it * 128, j0 = jt * 128;
    const int tid = threadIdx.x;
    const int lane = tid & 63, w = tid >> 6;
    const int wi = w & 1, wj = w >> 1;
    const int quad = lane >> 4, l15 = lane & 15;

    f32x4 acc[4][4] = {};

    // staging: per issue e (8 rows), lane l -> row e*8+(l>>3),
    // global chunk (l&7)^(l>>3), LDS slot lane*16 (contiguous)
    const int srow = lane >> 3;
    const int schunk = ((lane & 7) ^ srow) * 16;
    const uint8_t* gA = at8 + (size_t)(i0 + w * 32 + srow) * CDIM + schunk;
    const uint8_t* gB = bn8 + (size_t)(j0 + w * 32 + srow) * CDIM + schunk;
    uint8_t* lA = &Al[w * 32 * 128];
    uint8_t* lB = &Bl[w * 32 * 128];

    // frag-read physical chunk for logical chunk 2*quad at row r: (2q)^(r&7)
    const int rc0 = ((2 * quad) ^ (l15 & 7)) * 16;

    for (int kk = 0; kk < CDIM; kk += 128) {
#pragma unroll
        for (int e = 0; e < 4; ++e) {
            async16(gA + kk + e * 8 * CDIM, lA + e * 1024);
            async16(gB + kk + e * 8 * CDIM, lB + e * 1024);
        }
        __syncthreads();

        i32x8 bg[4];
#pragma unroll
        for (int n = 0; n < 4; ++n) {
            const int rb = (wj * 64 + n * 16 + l15) * 128;
            u32x4 lo = *(const u32x4*)&Bl[rb + rc0];
            u32x4 hi = *(const u32x4*)&Bl[rb + (rc0 ^ 16)];
            bg[n] = (i32x8){(int)lo.x, (int)lo.y, (int)lo.z, (int)lo.w,
                            (int)hi.x, (int)hi.y, (int)hi.z, (int)hi.w};
        }
#pragma unroll
        for (int m = 0; m < 4; ++m) {
            const int rb = (wi * 64 + m * 16 + l15) * 128;
            u32x4 lo = *(const u32x4*)&Al[rb + rc0];
            u32x4 hi = *(const u32x4*)&Al[rb + (rc0 ^ 16)];
            i32x8 af = (i32x8){(int)lo.x, (int)lo.y, (int)lo.z, (int)lo.w,
                               (int)hi.x, (int)hi.y, (int)hi.z, (int)hi.w};
#pragma unroll
            for (int n = 0; n < 4; ++n)
                acc[m][n] = __builtin_amdgcn_mfma_scale_f32_16x16x128_f8f6f4(
                    af, bg[n], acc[m][n],
                    0, 0,                       // cbsz=FP8, blgp=FP8
                    0, 0x7F7F7F7F,              // opsel_a, scale_a = 1.0 (E8M0)
                    0, 0x7F7F7F7F);             // opsel_b, scale_b = 1.0
        }
        __syncthreads();
    }

    // epilogue: normalize by per-j denom, then argmax over this block's j's
    float invd[4];
#pragma unroll
    for (int n = 0; n < 4; ++n) {
        float sq = sumsq_b[j0 + wj * 64 + n * 16 + l15];
        invd[n] = 1.0f / (sqrtf(sq + EPSF) + EPSF);
    }
#pragma unroll
    for (int m = 0; m < 4; ++m) {
#pragma unroll
        for (int r = 0; r < 4; ++r) {
            float v = acc[m][0][r] * invd[0];
            int j = j0 + wj * 64 + l15;
#pragma unroll
            for (int n = 1; n < 4; ++n) {
                float vn = acc[m][n][r] * invd[n];
                int jn = j0 + wj * 64 + n * 16 + l15;
                if (vn > v) { v = vn; j = jn; }   // strict >: keeps smallest j
            }
#pragma unroll
            for (int msk = 1; msk < 16; msk <<= 1) {
                float ov = __shfl_xor(v, msk, 64);
                int   oj = __shfl_xor(j, msk, 64);
                if (ov > v || (ov == v && oj < j)) { v = ov; j = oj; }
            }
            if (l15 == 0) {
                int gi = i0 + wi * 64 + m * 16 + quad * 4 + r;
                uint32_t u = __float_as_uint(v);
                u = (u & 0x80000000u) ? ~u : (u | 0x80000000u);  // orderable f32
                unsigned long long packed =
                    ((unsigned long long)u << 32) | (uint32_t)(~(uint32_t)j);
                atomicMax(&best[gi], packed);  // ties -> larger ~j -> smaller j
            }
        }
    }
}

// ---- Kernel 3: final loss from stored argmax dot (no gather) ----
// stored v = 128 * dot(a_i, b_j) / denom_b[j]  (fp8 dot, fp32 denom)
__global__ void loss_reduce(const unsigned long long* __restrict__ best,
                            const float* __restrict__ sumsq_a,
                            const float* __restrict__ sumsq_b,
                            float* __restrict__ out) {
    int i = blockIdx.x * 256 + threadIdx.x;
    unsigned long long pk = best[i];
    uint32_t x = (uint32_t)(pk >> 32);
    float v = (x & 0x80000000u) ? __uint_as_float(x & 0x7fffffffu)
                                : __uint_as_float(~x);
    int j = (int)(~(uint32_t)pk);
    float sb = sumsq_b[j];
    float denb = sqrtf(sb + EPSF) + EPSF;
    float dot = v * denb * (1.0f / 128.0f);
    float cs = dot / ((sqrtf(sumsq_a[i]) + EPSF) * (sqrtf(sb) + EPSF));
    float term = 1.0f - cs;
#pragma unroll
    for (int m = 32; m; m >>= 1) term += __shfl_down(term, m, 64);
    __shared__ float red[4];
    int wv = threadIdx.x >> 6, lane = threadIdx.x & 63;
    if (lane == 0) red[wv] = term;
    __syncthreads();
    if (threadIdx.x == 0) {
        float ssum = (red[0] + red[1] + red[2] + red[3]) * (1.0f / HW);
        atomicAdd(out, ssum);
    }
}

extern "C" void kernel_launch(void* const* d_in, const int* in_sizes, int n_in,
                              void* d_out, int out_size, void* d_ws, size_t ws_size,
                              hipStream_t stream) {
    const float* a = (const float*)d_in[0];
    const float* b = (const float*)d_in[1];
    char* ws = (char*)d_ws;

    const size_t T_BYTES = (size_t)HW * CDIM;   // 12.58 MB per fp8 matrix
    uint8_t* at8 = (uint8_t*)ws;
    uint8_t* bn8 = (uint8_t*)(ws + T_BYTES);
    float* sumsq_a = (float*)(ws + 2 * T_BYTES);
    float* sumsq_b = (float*)(ws + 2 * T_BYTES + HW * sizeof(float));
    unsigned long long* best =
        (unsigned long long*)(ws + 2 * T_BYTES + 2 * HW * sizeof(float));

    // zero sumsq_a + sumsq_b + best in one contiguous memset
    hipMemsetAsync(sumsq_a, 0, 2 * HW * sizeof(float) + HW * sizeof(unsigned long long),
                   stream);
    hipMemsetAsync(d_out, 0, out_size * sizeof(float), stream);

    dim3 tg(HW / 64, CDIM / 64, 2);
    transpose_fp8_norm<<<tg, 256, 0, stream>>>(a, b, at8, bn8, sumsq_a, sumsq_b);
    gemm_argmax<<<(HW / 128) * (HW / 128), 256, 0, stream>>>(at8, bn8, sumsq_b, best);
    loss_reduce<<<HW / 256, 256, 0, stream>>>(best, sumsq_a, sumsq_b, (float*)d_out);
}

// Round 8
// 2021.026 us; speedup vs baseline: 1.1955x; 1.1955x over previous
//
#include <hip/hip_runtime.h>
#include <stdint.h>

#define HW 16384
#define CDIM 768
#define EPSF 1e-8f

typedef float f32x4 __attribute__((ext_vector_type(4)));
typedef int   i32x8 __attribute__((ext_vector_type(8)));
typedef uint32_t u32x4 __attribute__((ext_vector_type(4)));

__device__ inline void async16(const void* g, void* l) {
    __builtin_amdgcn_global_load_lds(
        (const __attribute__((address_space(1))) uint32_t*)g,
        (__attribute__((address_space(3))) uint32_t*)l, 16, 0, 0);
}

__device__ inline uint32_t pk4_fp8(float v0, float v1, float v2, float v3) {
    uint32_t r = __builtin_amdgcn_cvt_pk_fp8_f32(v0, v1, 0, false);
    r = __builtin_amdgcn_cvt_pk_fp8_f32(v2, v3, r, true);
    return r;   // bytes [v0,v1,v2,v3] little-endian
}

// ---- Kernel 1: fused transpose [C][HW] fp32 -> [HW][C] fp8 + column sum-sq ----
// z=0: a (scale x16), z=1: b (scale x8, RAW; normalization in GEMM epilogue).
__global__ void __launch_bounds__(256)
transpose_fp8_norm(const float* __restrict__ a, const float* __restrict__ b,
                   uint8_t* __restrict__ at8, uint8_t* __restrict__ bn8,
                   float* __restrict__ sumsq_a, float* __restrict__ sumsq_b) {
    const int z = blockIdx.z;
    const float* src = z ? b : a;
    uint8_t* dst = z ? bn8 : at8;
    float* sums = z ? sumsq_b : sumsq_a;
    const float mult = z ? 8.0f : 16.0f;

    __shared__ float tile[64][65];   // [channel][spatial], +1 pad
    const int s0 = blockIdx.x * 64, c0 = blockIdx.y * 64;
    const int tx = threadIdx.x & 63, ty = threadIdx.x >> 6;
#pragma unroll
    for (int p = 0; p < 16; ++p) {
        int cl = p * 4 + ty;
        tile[cl][tx] = src[(size_t)(c0 + cl) * HW + s0 + tx];
    }
    __syncthreads();

    const int chgrp = tx & 15, rowsub = tx >> 4;
    uint32_t* dst32 = (uint32_t*)dst;
#pragma unroll
    for (int p = 0; p < 4; ++p) {
        int sl = p * 16 + ty * 4 + rowsub;
        float v0 = tile[chgrp * 4 + 0][sl];
        float v1 = tile[chgrp * 4 + 1][sl];
        float v2 = tile[chgrp * 4 + 2][sl];
        float v3 = tile[chgrp * 4 + 3][sl];
        float part = v0 * v0 + v1 * v1 + v2 * v2 + v3 * v3;  // raw sum-sq
        dst32[(size_t)(s0 + sl) * (CDIM / 4) + (c0 >> 2) + chgrp] =
            pk4_fp8(v0 * mult, v1 * mult, v2 * mult, v3 * mult);
#pragma unroll
        for (int m = 1; m < 16; m <<= 1) part += __shfl_xor(part, m, 64);
        if (chgrp == 0) atomicAdd(&sums[s0 + sl], part);
    }
}

// ---- Kernel 2: MX-scaled fp8 GEMM (K=128) + normalize + argmax epilogue ----
// Round-7 structure with the spill fixed: launch_bounds(256,3) gives a
// ~170-reg budget (64 AGPR acc + ~75 arch VGPRs fits; (256,4)'s 128-reg cap
// spilled acc/frags to scratch -> 10 GB of HBM spill traffic, 2.3 ms).
// Registers (not LDS: 32 KB -> 5 blocks) set occupancy at 3 blocks/CU --
// the round-2/3 proven operating point. Frag tuples are filled by writing
// two u32x4 halves (two ds_read_b128) directly into i32x8 storage.
// E8M0 scales = 127 (x1.0): numerics identical to plain fp8.
__global__ void __launch_bounds__(256, 3)
gemm_argmax(const uint8_t* __restrict__ at8, const uint8_t* __restrict__ bn8,
            const float* __restrict__ sumsq_b,
            unsigned long long* __restrict__ best) {
    __shared__ uint8_t Al[128 * 128];
    __shared__ uint8_t Bl[128 * 128];

    const int g = blockIdx.x;          // 0..16383
    const int xcd    = g & 7;
    const int s      = g >> 3;
    const int super  = s >> 5;         // 32 blocks / supertile
    const int within = s & 31;
    const int si = super >> 4;         // 4 i-tiles per supertile row
    const int sj = super & 15;         // 8 j-tiles per supertile col
    const int it = xcd * 16 + si * 4 + (within & 3);
    const int jt = sj * 8 + (within >> 2);

    const int i0 = it * 128, j0 = jt * 128;
    const int tid = threadIdx.x;
    const int lane = tid & 63, w = tid >> 6;
    const int wi = w & 1, wj = w >> 1;
    const int quad = lane >> 4, l15 = lane & 15;

    f32x4 acc[4][4] = {};

    // staging: per issue e (8 rows), lane l -> row e*8+(l>>3),
    // global chunk (l&7)^(l>>3), LDS slot lane*16 (contiguous)
    const int srow = lane >> 3;
    const int schunk = ((lane & 7) ^ srow) * 16;
    const uint8_t* gA = at8 + (size_t)(i0 + w * 32 + srow) * CDIM + schunk;
    const uint8_t* gB = bn8 + (size_t)(j0 + w * 32 + srow) * CDIM + schunk;
    uint8_t* lA = &Al[w * 32 * 128];
    uint8_t* lB = &Bl[w * 32 * 128];

    // frag-read physical chunk for logical chunk 2*quad at row r: (2q)^(r&7)
    const int rc0 = ((2 * quad) ^ (l15 & 7)) * 16;

    for (int kk = 0; kk < CDIM; kk += 128) {
#pragma unroll
        for (int e = 0; e < 4; ++e) {
            async16(gA + kk + e * 8 * CDIM, lA + e * 1024);
            async16(gB + kk + e * 8 * CDIM, lB + e * 1024);
        }
        __syncthreads();

        i32x8 bg[4];
#pragma unroll
        for (int n = 0; n < 4; ++n) {
            const int rb = (wj * 64 + n * 16 + l15) * 128;
            *(u32x4*)&bg[n]       = *(const u32x4*)&Bl[rb + rc0];
            *((u32x4*)&bg[n] + 1) = *(const u32x4*)&Bl[rb + (rc0 ^ 16)];
        }
#pragma unroll
        for (int m = 0; m < 4; ++m) {
            const int rb = (wi * 64 + m * 16 + l15) * 128;
            i32x8 af;
            *(u32x4*)&af       = *(const u32x4*)&Al[rb + rc0];
            *((u32x4*)&af + 1) = *(const u32x4*)&Al[rb + (rc0 ^ 16)];
#pragma unroll
            for (int n = 0; n < 4; ++n)
                acc[m][n] = __builtin_amdgcn_mfma_scale_f32_16x16x128_f8f6f4(
                    af, bg[n], acc[m][n],
                    0, 0,                       // cbsz=FP8, blgp=FP8
                    0, 0x7F7F7F7F,              // opsel_a, scale_a = 1.0 (E8M0)
                    0, 0x7F7F7F7F);             // opsel_b, scale_b = 1.0
        }
        __syncthreads();
    }

    // epilogue: normalize by per-j denom, then argmax over this block's j's
    float invd[4];
#pragma unroll
    for (int n = 0; n < 4; ++n) {
        float sq = sumsq_b[j0 + wj * 64 + n * 16 + l15];
        invd[n] = 1.0f / (sqrtf(sq + EPSF) + EPSF);
    }
#pragma unroll
    for (int m = 0; m < 4; ++m) {
#pragma unroll
        for (int r = 0; r < 4; ++r) {
            float v = acc[m][0][r] * invd[0];
            int j = j0 + wj * 64 + l15;
#pragma unroll
            for (int n = 1; n < 4; ++n) {
                float vn = acc[m][n][r] * invd[n];
                int jn = j0 + wj * 64 + n * 16 + l15;
                if (vn > v) { v = vn; j = jn; }   // strict >: keeps smallest j
            }
#pragma unroll
            for (int msk = 1; msk < 16; msk <<= 1) {
                float ov = __shfl_xor(v, msk, 64);
                int   oj = __shfl_xor(j, msk, 64);
                if (ov > v || (ov == v && oj < j)) { v = ov; j = oj; }
            }
            if (l15 == 0) {
                int gi = i0 + wi * 64 + m * 16 + quad * 4 + r;
                uint32_t u = __float_as_uint(v);
                u = (u & 0x80000000u) ? ~u : (u | 0x80000000u);  // orderable f32
                unsigned long long packed =
                    ((unsigned long long)u << 32) | (uint32_t)(~(uint32_t)j);
                atomicMax(&best[gi], packed);  // ties -> larger ~j -> smaller j
            }
        }
    }
}

// ---- Kernel 3: final loss from stored argmax dot (no gather) ----
// stored v = 128 * dot(a_i, b_j) / denom_b[j]  (fp8 dot, fp32 denom)
__global__ void loss_reduce(const unsigned long long* __restrict__ best,
                            const float* __restrict__ sumsq_a,
                            const float* __restrict__ sumsq_b,
                            float* __restrict__ out) {
    int i = blockIdx.x * 256 + threadIdx.x;
    unsigned long long pk = best[i];
    uint32_t x = (uint32_t)(pk >> 32);
    float v = (x & 0x80000000u) ? __uint_as_float(x & 0x7fffffffu)
                                : __uint_as_float(~x);
    int j = (int)(~(uint32_t)pk);
    float sb = sumsq_b[j];
    float denb = sqrtf(sb + EPSF) + EPSF;
    float dot = v * denb * (1.0f / 128.0f);
    float cs = dot / ((sqrtf(sumsq_a[i]) + EPSF) * (sqrtf(sb) + EPSF));
    float term = 1.0f - cs;
#pragma unroll
    for (int m = 32; m; m >>= 1) term += __shfl_down(term, m, 64);
    __shared__ float red[4];
    int wv = threadIdx.x >> 6, lane = threadIdx.x & 63;
    if (lane == 0) red[wv] = term;
    __syncthreads();
    if (threadIdx.x == 0) {
        float ssum = (red[0] + red[1] + red[2] + red[3]) * (1.0f / HW);
        atomicAdd(out, ssum);
    }
}

extern "C" void kernel_launch(void* const* d_in, const int* in_sizes, int n_in,
                              void* d_out, int out_size, void* d_ws, size_t ws_size,
                              hipStream_t stream) {
    const float* a = (const float*)d_in[0];
    const float* b = (const float*)d_in[1];
    char* ws = (char*)d_ws;

    const size_t T_BYTES = (size_t)HW * CDIM;   // 12.58 MB per fp8 matrix
    uint8_t* at8 = (uint8_t*)ws;
    uint8_t* bn8 = (uint8_t*)(ws + T_BYTES);
    float* sumsq_a = (float*)(ws + 2 * T_BYTES);
    float* sumsq_b = (float*)(ws + 2 * T_BYTES + HW * sizeof(float));
    unsigned long long* best =
        (unsigned long long*)(ws + 2 * T_BYTES + 2 * HW * sizeof(float));

    // zero sumsq_a + sumsq_b + best in one contiguous memset
    hipMemsetAsync(sumsq_a, 0, 2 * HW * sizeof(float) + HW * sizeof(unsigned long long),
                   stream);
    hipMemsetAsync(d_out, 0, out_size * sizeof(float), stream);

    dim3 tg(HW / 64, CDIM / 64, 2);
    transpose_fp8_norm<<<tg, 256, 0, stream>>>(a, b, at8, bn8, sumsq_a, sumsq_b);
    gemm_argmax<<<(HW / 128) * (HW / 128), 256, 0, stream>>>(at8, bn8, sumsq_b, best);
    loss_reduce<<<HW / 256, 256, 0, stream>>>(best, sumsq_a, sumsq_b, (float*)d_out);
}

// Round 9
// 518.532 us; speedup vs baseline: 4.6594x; 3.8976x over previous
//
#include <hip/hip_runtime.h>
#include <stdint.h>

#define HW 16384
#define CDIM 768
#define EPSF 1e-8f

typedef float f32x4 __attribute__((ext_vector_type(4)));
typedef int   i32x8 __attribute__((ext_vector_type(8)));
typedef uint32_t u32x4 __attribute__((ext_vector_type(4)));

__device__ inline void async16(const void* g, void* l) {
    __builtin_amdgcn_global_load_lds(
        (const __attribute__((address_space(1))) uint32_t*)g,
        (__attribute__((address_space(3))) uint32_t*)l, 16, 0, 0);
}

__device__ inline uint32_t pk4_fp8(float v0, float v1, float v2, float v3) {
    uint32_t r = __builtin_amdgcn_cvt_pk_fp8_f32(v0, v1, 0, false);
    r = __builtin_amdgcn_cvt_pk_fp8_f32(v2, v3, r, true);
    return r;   // bytes [v0,v1,v2,v3] little-endian
}

// ---- Kernel 1: fused transpose [C][HW] fp32 -> [HW][C] fp8 + column sum-sq ----
// z=0: a (scale x16), z=1: b (scale x8, RAW; normalization in GEMM epilogue).
__global__ void __launch_bounds__(256)
transpose_fp8_norm(const float* __restrict__ a, const float* __restrict__ b,
                   uint8_t* __restrict__ at8, uint8_t* __restrict__ bn8,
                   float* __restrict__ sumsq_a, float* __restrict__ sumsq_b) {
    const int z = blockIdx.z;
    const float* src = z ? b : a;
    uint8_t* dst = z ? bn8 : at8;
    float* sums = z ? sumsq_b : sumsq_a;
    const float mult = z ? 8.0f : 16.0f;

    __shared__ float tile[64][65];   // [channel][spatial], +1 pad
    const int s0 = blockIdx.x * 64, c0 = blockIdx.y * 64;
    const int tx = threadIdx.x & 63, ty = threadIdx.x >> 6;
#pragma unroll
    for (int p = 0; p < 16; ++p) {
        int cl = p * 4 + ty;
        tile[cl][tx] = src[(size_t)(c0 + cl) * HW + s0 + tx];
    }
    __syncthreads();

    const int chgrp = tx & 15, rowsub = tx >> 4;
    uint32_t* dst32 = (uint32_t*)dst;
#pragma unroll
    for (int p = 0; p < 4; ++p) {
        int sl = p * 16 + ty * 4 + rowsub;
        float v0 = tile[chgrp * 4 + 0][sl];
        float v1 = tile[chgrp * 4 + 1][sl];
        float v2 = tile[chgrp * 4 + 2][sl];
        float v3 = tile[chgrp * 4 + 3][sl];
        float part = v0 * v0 + v1 * v1 + v2 * v2 + v3 * v3;  // raw sum-sq
        dst32[(size_t)(s0 + sl) * (CDIM / 4) + (c0 >> 2) + chgrp] =
            pk4_fp8(v0 * mult, v1 * mult, v2 * mult, v3 * mult);
#pragma unroll
        for (int m = 1; m < 16; m <<= 1) part += __shfl_xor(part, m, 64);
        if (chgrp == 0) atomicAdd(&sums[s0 + sl], part);
    }
}

// ---- Kernel 2: MX-scaled fp8 GEMM (K=128) + normalize + argmax epilogue ----
// Spill root-cause (rounds 7/8): FIVE live 8-wide i32x8 tuples (bg[4]+af)
// fragmented the unified RF -> RA spilled all frags every iter (900 B/thread
// scratch, 8.5 GB HBM). Fix: n-outer/m-inner loop keeps AT MOST TWO 8-wide
// tuples live (one bg, one transient af); A frags re-read from LDS 4x
// (LDS-issue floor ~77us < MX MFMA floor ~89us -> free). No launch_bounds
// (LDS 32 KB caps blocks; let RA pick). kk loop pinned unroll 1 so live
// ranges stay iteration-local. E8M0 scales = 127 (x1.0): plain-fp8 numerics.
// Chunk-XOR swizzle as before (2.5e7 conflict cycles measured = fine).
__global__ void
gemm_argmax(const uint8_t* __restrict__ at8, const uint8_t* __restrict__ bn8,
            const float* __restrict__ sumsq_b,
            unsigned long long* __restrict__ best) {
    __shared__ uint8_t Al[128 * 128];
    __shared__ uint8_t Bl[128 * 128];

    const int g = blockIdx.x;          // 0..16383
    const int xcd    = g & 7;
    const int s      = g >> 3;
    const int super  = s >> 5;         // 32 blocks / supertile
    const int within = s & 31;
    const int si = super >> 4;         // 4 i-tiles per supertile row
    const int sj = super & 15;         // 8 j-tiles per supertile col
    const int it = xcd * 16 + si * 4 + (within & 3);
    const int jt = sj * 8 + (within >> 2);

    const int i0 = it * 128, j0 = jt * 128;
    const int tid = threadIdx.x;
    const int lane = tid & 63, w = tid >> 6;
    const int wi = w & 1, wj = w >> 1;
    const int quad = lane >> 4, l15 = lane & 15;

    f32x4 acc[4][4] = {};

    // staging: per issue e (8 rows), lane l -> row e*8+(l>>3),
    // global chunk (l&7)^(l>>3), LDS slot lane*16 (contiguous)
    const int srow = lane >> 3;
    const int schunk = ((lane & 7) ^ srow) * 16;
    const uint8_t* gA = at8 + (size_t)(i0 + w * 32 + srow) * CDIM + schunk;
    const uint8_t* gB = bn8 + (size_t)(j0 + w * 32 + srow) * CDIM + schunk;
    uint8_t* lA = &Al[w * 32 * 128];
    uint8_t* lB = &Bl[w * 32 * 128];

    // frag-read physical chunk for logical chunk 2*quad at row r: (2q)^(r&7)
    const int rc0 = ((2 * quad) ^ (l15 & 7)) * 16;

#pragma unroll 1
    for (int kk = 0; kk < CDIM; kk += 128) {
#pragma unroll
        for (int e = 0; e < 4; ++e) {
            async16(gA + kk + e * 8 * CDIM, lA + e * 1024);
            async16(gB + kk + e * 8 * CDIM, lB + e * 1024);
        }
        __syncthreads();

#pragma unroll
        for (int n = 0; n < 4; ++n) {
            const int rbB = (wj * 64 + n * 16 + l15) * 128;
            i32x8 bg;
            *(u32x4*)&bg       = *(const u32x4*)&Bl[rbB + rc0];
            *((u32x4*)&bg + 1) = *(const u32x4*)&Bl[rbB + (rc0 ^ 16)];
#pragma unroll
            for (int m = 0; m < 4; ++m) {
                const int rbA = (wi * 64 + m * 16 + l15) * 128;
                i32x8 af;
                *(u32x4*)&af       = *(const u32x4*)&Al[rbA + rc0];
                *((u32x4*)&af + 1) = *(const u32x4*)&Al[rbA + (rc0 ^ 16)];
                acc[m][n] = __builtin_amdgcn_mfma_scale_f32_16x16x128_f8f6f4(
                    af, bg, acc[m][n],
                    0, 0,                       // cbsz=FP8, blgp=FP8
                    0, 0x7F7F7F7F,              // opsel_a, scale_a = 1.0 (E8M0)
                    0, 0x7F7F7F7F);             // opsel_b, scale_b = 1.0
            }
        }
        __syncthreads();
    }

    // epilogue: normalize by per-j denom, then argmax over this block's j's
    float invd[4];
#pragma unroll
    for (int n = 0; n < 4; ++n) {
        float sq = sumsq_b[j0 + wj * 64 + n * 16 + l15];
        invd[n] = 1.0f / (sqrtf(sq + EPSF) + EPSF);
    }
#pragma unroll
    for (int m = 0; m < 4; ++m) {
#pragma unroll
        for (int r = 0; r < 4; ++r) {
            float v = acc[m][0][r] * invd[0];
            int j = j0 + wj * 64 + l15;
#pragma unroll
            for (int n = 1; n < 4; ++n) {
                float vn = acc[m][n][r] * invd[n];
                int jn = j0 + wj * 64 + n * 16 + l15;
                if (vn > v) { v = vn; j = jn; }   // strict >: keeps smallest j
            }
#pragma unroll
            for (int msk = 1; msk < 16; msk <<= 1) {
                float ov = __shfl_xor(v, msk, 64);
                int   oj = __shfl_xor(j, msk, 64);
                if (ov > v || (ov == v && oj < j)) { v = ov; j = oj; }
            }
            if (l15 == 0) {
                int gi = i0 + wi * 64 + m * 16 + quad * 4 + r;
                uint32_t u = __float_as_uint(v);
                u = (u & 0x80000000u) ? ~u : (u | 0x80000000u);  // orderable f32
                unsigned long long packed =
                    ((unsigned long long)u << 32) | (uint32_t)(~(uint32_t)j);
                atomicMax(&best[gi], packed);  // ties -> larger ~j -> smaller j
            }
        }
    }
}

// ---- Kernel 3: final loss from stored argmax dot (no gather) ----
// stored v = 128 * dot(a_i, b_j) / denom_b[j]  (fp8 dot, fp32 denom)
__global__ void loss_reduce(const unsigned long long* __restrict__ best,
                            const float* __restrict__ sumsq_a,
                            const float* __restrict__ sumsq_b,
                            float* __restrict__ out) {
    int i = blockIdx.x * 256 + threadIdx.x;
    unsigned long long pk = best[i];
    uint32_t x = (uint32_t)(pk >> 32);
    float v = (x & 0x80000000u) ? __uint_as_float(x & 0x7fffffffu)
                                : __uint_as_float(~x);
    int j = (int)(~(uint32_t)pk);
    float sb = sumsq_b[j];
    float denb = sqrtf(sb + EPSF) + EPSF;
    float dot = v * denb * (1.0f / 128.0f);
    float cs = dot / ((sqrtf(sumsq_a[i]) + EPSF) * (sqrtf(sb) + EPSF));
    float term = 1.0f - cs;
#pragma unroll
    for (int m = 32; m; m >>= 1) term += __shfl_down(term, m, 64);
    __shared__ float red[4];
    int wv = threadIdx.x >> 6, lane = threadIdx.x & 63;
    if (lane == 0) red[wv] = term;
    __syncthreads();
    if (threadIdx.x == 0) {
        float ssum = (red[0] + red[1] + red[2] + red[3]) * (1.0f / HW);
        atomicAdd(out, ssum);
    }
}

extern "C" void kernel_launch(void* const* d_in, const int* in_sizes, int n_in,
                              void* d_out, int out_size, void* d_ws, size_t ws_size,
                              hipStream_t stream) {
    const float* a = (const float*)d_in[0];
    const float* b = (const float*)d_in[1];
    char* ws = (char*)d_ws;

    const size_t T_BYTES = (size_t)HW * CDIM;   // 12.58 MB per fp8 matrix
    uint8_t* at8 = (uint8_t*)ws;
    uint8_t* bn8 = (uint8_t*)(ws + T_BYTES);
    float* sumsq_a = (float*)(ws + 2 * T_BYTES);
    float* sumsq_b = (float*)(ws + 2 * T_BYTES + HW * sizeof(float));
    unsigned long long* best =
        (unsigned long long*)(ws + 2 * T_BYTES + 2 * HW * sizeof(float));

    // zero sumsq_a + sumsq_b + best in one contiguous memset
    hipMemsetAsync(sumsq_a, 0, 2 * HW * sizeof(float) + HW * sizeof(unsigned long long),
                   stream);
    hipMemsetAsync(d_out, 0, out_size * sizeof(float), stream);

    dim3 tg(HW / 64, CDIM / 64, 2);
    transpose_fp8_norm<<<tg, 256, 0, stream>>>(a, b, at8, bn8, sumsq_a, sumsq_b);
    gemm_argmax<<<(HW / 128) * (HW / 128), 256, 0, stream>>>(at8, bn8, sumsq_b, best);
    loss_reduce<<<HW / 256, 256, 0, stream>>>(best, sumsq_a, sumsq_b, (float*)d_out);
}